// Round 1
// baseline (1481.472 us; speedup 1.0000x reference)
//
#include <hip/hip_runtime.h>
#include <math.h>

#define Bsz 4
#define T 2048
#define D 128
#define H 8
#define HS 16
#define E 8
#define FF 512
#define N (Bsz*T)     // 8192
#define EPS 1e-5f
#define SCALE 0.25f   // 1/sqrt(16)

__device__ __forceinline__ float wave_sum(float v) {
#pragma unroll
  for (int off = 32; off >= 1; off >>= 1) v += __shfl_xor(v, off);
  return v;
}

// ---------------- LayerNorm: one wave per row of 128 ----------------
__global__ void ln_kernel(const float* __restrict__ x, const float* __restrict__ g,
                          const float* __restrict__ b, float* __restrict__ out) {
  int n = blockIdx.x;
  int tid = threadIdx.x;  // 64
  float2 v = ((const float2*)(x + n * D))[tid];
  float s  = wave_sum(v.x + v.y);
  float s2 = wave_sum(v.x * v.x + v.y * v.y);
  float m = s * (1.f / D);
  float var = s2 * (1.f / D) - m * m;
  float r = rsqrtf(var + EPS);
  float2 gg = ((const float2*)g)[tid];
  float2 bb = ((const float2*)b)[tid];
  float2 o;
  o.x = (v.x - m) * r * gg.x + bb.x;
  o.y = (v.y - m) * r * gg.y + bb.y;
  ((float2*)(out + n * D))[tid] = o;
}

// ---------------- QKV: 16 tokens/block, 384 threads (q|k|v x 128 outs) ----------------
__global__ void qkv_kernel(const float* __restrict__ xn, const float* __restrict__ wq,
                           const float* __restrict__ wk, const float* __restrict__ wv,
                           float* __restrict__ q, float* __restrict__ k, float* __restrict__ v) {
  __shared__ float xs[D][20];
  int n0 = blockIdx.x * 16;
  int tid = threadIdx.x;
  for (int idx = tid; idx < 16 * D; idx += 384) {
    int t = idx >> 7, d = idx & 127;
    xs[d][t] = xn[(n0 + t) * D + d];
  }
  __syncthreads();
  int grp = tid / 128;        // 0=q 1=k 2=v (wave-uniform)
  int o = tid & 127;
  int h = o >> 4, e = o & 15;
  const float* w = (grp == 0 ? wq : (grp == 1 ? wk : wv)) + h * D * HS + e;
  float acc[16];
#pragma unroll
  for (int t = 0; t < 16; ++t) acc[t] = 0.f;
  for (int d = 0; d < D; ++d) {
    float wv_ = w[d * HS];
    float4 a0 = *(const float4*)&xs[d][0];
    float4 a1 = *(const float4*)&xs[d][4];
    float4 a2 = *(const float4*)&xs[d][8];
    float4 a3 = *(const float4*)&xs[d][12];
    float xv[16] = {a0.x,a0.y,a0.z,a0.w, a1.x,a1.y,a1.z,a1.w,
                    a2.x,a2.y,a2.z,a2.w, a3.x,a3.y,a3.z,a3.w};
#pragma unroll
    for (int t = 0; t < 16; ++t) acc[t] += wv_ * xv[t];
  }
  float* dst = (grp == 0 ? q : (grp == 1 ? k : v));
  int b_ = n0 / T, t0 = n0 % T;
#pragma unroll
  for (int t = 0; t < 16; ++t)
    dst[((b_ * H + h) * T + t0 + t) * HS + e] = acc[t];
}

// ---------------- Flash attention: 1 wave = 64 queries, tiles of 64 keys ----------------
__global__ void attn_kernel(const float* __restrict__ q, const float* __restrict__ k,
                            const float* __restrict__ v, float* __restrict__ ao) {
  __shared__ float4 ks[64][5];
  __shared__ float4 vs[64][5];
  int bh = blockIdx.x >> 5;
  int qb = blockIdx.x & 31;
  int tid = threadIdx.x;  // 64
  int t = qb * 64 + tid;
  const float4* qp = (const float4*)(q + (bh * T + t) * HS);
  float qq[16];
  {
    float4 q0 = qp[0], q1 = qp[1], q2 = qp[2], q3 = qp[3];
    float tmp[16] = {q0.x,q0.y,q0.z,q0.w, q1.x,q1.y,q1.z,q1.w,
                     q2.x,q2.y,q2.z,q2.w, q3.x,q3.y,q3.z,q3.w};
#pragma unroll
    for (int m = 0; m < 16; ++m) qq[m] = tmp[m] * SCALE;
  }
  float acc[16];
#pragma unroll
  for (int e = 0; e < 16; ++e) acc[e] = 0.f;
  float mrun = -1e30f, l = 0.f;
  int ntile = qb + 1;
  for (int it = 0; it < ntile; ++it) {
    int s0 = it * 64;
    const float4* kp = (const float4*)(k + (bh * T + s0 + tid) * HS);
    const float4* vp = (const float4*)(v + (bh * T + s0 + tid) * HS);
    ks[tid][0] = kp[0]; ks[tid][1] = kp[1]; ks[tid][2] = kp[2]; ks[tid][3] = kp[3];
    vs[tid][0] = vp[0]; vs[tid][1] = vp[1]; vs[tid][2] = vp[2]; vs[tid][3] = vp[3];
    __syncthreads();
    float sc[64];
    float smax = -1e30f;
#pragma unroll
    for (int j = 0; j < 64; ++j) {
      float4 k0 = ks[j][0], k1 = ks[j][1], k2 = ks[j][2], k3 = ks[j][3];
      float kk[16] = {k0.x,k0.y,k0.z,k0.w, k1.x,k1.y,k1.z,k1.w,
                      k2.x,k2.y,k2.z,k2.w, k3.x,k3.y,k3.z,k3.w};
      float dot = 0.f;
#pragma unroll
      for (int m = 0; m < 16; ++m) dot += qq[m] * kk[m];
      sc[j] = (s0 + j <= t) ? dot : -1e30f;
      smax = fmaxf(smax, sc[j]);
    }
    float mn = fmaxf(mrun, smax);
    float corr = __expf(mrun - mn);
    l *= corr;
#pragma unroll
    for (int e = 0; e < 16; ++e) acc[e] *= corr;
    mrun = mn;
#pragma unroll
    for (int j = 0; j < 64; ++j) {
      float p = __expf(sc[j] - mrun);
      l += p;
      float4 v0 = vs[j][0], v1 = vs[j][1], v2 = vs[j][2], v3 = vs[j][3];
      float vv[16] = {v0.x,v0.y,v0.z,v0.w, v1.x,v1.y,v1.z,v1.w,
                      v2.x,v2.y,v2.z,v2.w, v3.x,v3.y,v3.z,v3.w};
#pragma unroll
      for (int e = 0; e < 16; ++e) acc[e] += p * vv[e];
    }
    __syncthreads();
  }
  float inv = 1.f / l;
  int b_ = bh >> 3, h = bh & 7;
  float* op = ao + (b_ * T + t) * D + h * HS;
#pragma unroll
  for (int m = 0; m < 4; ++m) {
    float4 o4 = {acc[4*m]*inv, acc[4*m+1]*inv, acc[4*m+2]*inv, acc[4*m+3]*inv};
    ((float4*)op)[m] = o4;
  }
}

// ---------------- proj + bias + residual: 16 tokens/block, 128 threads ----------------
__global__ void proj_kernel(const float* __restrict__ attn, const float* __restrict__ wp,
                            const float* __restrict__ bp, const float* __restrict__ x,
                            float* __restrict__ x1) {
  __shared__ float as_[D][20];
  int n0 = blockIdx.x * 16;
  int tid = threadIdx.x;  // 128
  for (int idx = tid; idx < 16 * D; idx += 128) {
    int t = idx >> 7, d = idx & 127;
    as_[d][t] = attn[(n0 + t) * D + d];
  }
  __syncthreads();
  float acc[16];
#pragma unroll
  for (int t = 0; t < 16; ++t) acc[t] = 0.f;
  for (int d = 0; d < D; ++d) {
    float w = wp[d * D + tid];
    float4 a0 = *(const float4*)&as_[d][0];
    float4 a1 = *(const float4*)&as_[d][4];
    float4 a2 = *(const float4*)&as_[d][8];
    float4 a3 = *(const float4*)&as_[d][12];
    float xv[16] = {a0.x,a0.y,a0.z,a0.w, a1.x,a1.y,a1.z,a1.w,
                    a2.x,a2.y,a2.z,a2.w, a3.x,a3.y,a3.z,a3.w};
#pragma unroll
    for (int t = 0; t < 16; ++t) acc[t] += w * xv[t];
  }
  float bb = bp[tid];
#pragma unroll
  for (int t = 0; t < 16; ++t) {
    int idx = (n0 + t) * D + tid;
    x1[idx] = x[idx] + acc[t] + bb;
  }
}

// ---------------- gate: softmax(8), top-2, expert bucketing, aux partials ----------------
__global__ void gate_kernel(const float* __restrict__ xn2, const float* __restrict__ wg,
                            float* __restrict__ psum, int* __restrict__ ecnt,
                            int* __restrict__ ltok, float* __restrict__ lgw) {
  int lane = threadIdx.x;  // 64
  int n = blockIdx.x * 64 + lane;
  const float4* xr = (const float4*)(xn2 + n * D);
  float lg[E];
#pragma unroll
  for (int e = 0; e < E; ++e) lg[e] = 0.f;
  for (int dq = 0; dq < 32; ++dq) {
    float4 xv = xr[dq];
    int d = dq * 4;
#pragma unroll
    for (int e = 0; e < E; ++e)
      lg[e] += xv.x * wg[d*E + e] + xv.y * wg[(d+1)*E + e]
             + xv.z * wg[(d+2)*E + e] + xv.w * wg[(d+3)*E + e];
  }
  float mx = lg[0];
#pragma unroll
  for (int e = 1; e < E; ++e) mx = fmaxf(mx, lg[e]);
  float p[E]; float s = 0.f;
#pragma unroll
  for (int e = 0; e < E; ++e) { p[e] = __expf(lg[e] - mx); s += p[e]; }
  float invs = 1.f / s;
#pragma unroll
  for (int e = 0; e < E; ++e) p[e] *= invs;
#pragma unroll
  for (int e = 0; e < E; ++e) {
    float ve = wave_sum(p[e]);
    if (lane == 0) atomicAdd(&psum[e], ve);
  }
  int i1 = 0; float p1 = p[0];
#pragma unroll
  for (int e = 1; e < E; ++e) if (p[e] > p1) { p1 = p[e]; i1 = e; }
  int i2 = (i1 == 0) ? 1 : 0; float p2 = p[i2];
#pragma unroll
  for (int e = 0; e < E; ++e) if (e != i1 && p[e] > p2) { p2 = p[e]; i2 = e; }
  float gden = 1.f / (p1 + p2);
  for (int kk = 0; kk < 2; ++kk) {
    int ei = kk ? i2 : i1;
    float g = (kk ? p2 : p1) * gden;
#pragma unroll
    for (int e = 0; e < E; ++e) {
      unsigned long long msk = __ballot(ei == e);
      if (msk == 0) continue;
      int cnt = __popcll(msk);
      int leader = __ffsll(msk) - 1;
      int base = 0;
      if (lane == leader) base = atomicAdd(&ecnt[e], cnt);
      base = __shfl(base, leader);
      if (ei == e) {
        int off = __popcll(msk & ((1ULL << lane) - 1ULL));
        ltok[e * N + base + off] = n;
        lgw[e * N + base + off] = g;
      }
    }
  }
}

// ---------------- grouped expert FFN: 64 tokens x 1 expert per block, 256 thr ----------------
__global__ __launch_bounds__(256) void moe_kernel(
    const float* __restrict__ xn2, const float* __restrict__ w1,
    const float* __restrict__ b1, const float* __restrict__ w2,
    const float* __restrict__ b2, const int* __restrict__ ecnt,
    const int* __restrict__ ltok, const float* __restrict__ lgw,
    float* __restrict__ ff) {
  int e = blockIdx.y;
  int cnt = ecnt[e];
  int t0 = blockIdx.x * 64;
  if (t0 >= cnt) return;
  int nt = min(64, cnt - t0);
  __shared__ float xT[D][68];
  __shared__ float hT[128][68];
  __shared__ int toks[64];
  __shared__ float gws[64];
  int tid = threadIdx.x;
  if (tid < 64) {
    if (tid < nt) { toks[tid] = ltok[e * N + t0 + tid]; gws[tid] = lgw[e * N + t0 + tid]; }
    else          { toks[tid] = -1; gws[tid] = 0.f; }
  }
  __syncthreads();
  {
    int i = tid >> 2, c = tid & 3;
    int tok = toks[i];
    const float* src = xn2 + (tok < 0 ? 0 : tok) * D;
    for (int j = 0; j < 32; ++j) {
      int d = c * 32 + j;
      xT[d][i] = (tok >= 0) ? src[d] : 0.f;
    }
  }
  __syncthreads();
  int l = tid & 31;
  int ib = (tid >> 5) * 8;
  float accO[4][8];
#pragma unroll
  for (int kk = 0; kk < 4; ++kk)
#pragma unroll
    for (int i = 0; i < 8; ++i) accO[kk][i] = 0.f;
  const float* w1e = w1 + e * D * FF;
  const float* w2e = w2 + e * FF * D;
  const float* b1e = b1 + e * FF;
  for (int fc = 0; fc < 4; ++fc) {
    int f0 = fc * 128;
    float accH[4][8];
#pragma unroll
    for (int kk = 0; kk < 4; ++kk)
#pragma unroll
      for (int i = 0; i < 8; ++i) accH[kk][i] = 0.f;
    for (int d = 0; d < D; ++d) {
      float4 xa = *(const float4*)&xT[d][ib];
      float4 xb = *(const float4*)&xT[d][ib + 4];
      float xv[8] = {xa.x,xa.y,xa.z,xa.w, xb.x,xb.y,xb.z,xb.w};
      const float* wp = w1e + d * FF + f0 + l;
      float wv4[4] = {wp[0], wp[32], wp[64], wp[96]};
#pragma unroll
      for (int kk = 0; kk < 4; ++kk)
#pragma unroll
        for (int i = 0; i < 8; ++i) accH[kk][i] += wv4[kk] * xv[i];
    }
    __syncthreads();   // prev phase-2 hT reads done
#pragma unroll
    for (int kk = 0; kk < 4; ++kk) {
      int fl = l + kk * 32;
      float bb = b1e[f0 + fl];
      float hv[8];
#pragma unroll
      for (int i = 0; i < 8; ++i) {
        float z = accH[kk][i] + bb;
        hv[i] = 0.5f * z * (1.f + erff(z * 0.70710678f));
      }
      float4 h0 = {hv[0],hv[1],hv[2],hv[3]};
      float4 h1 = {hv[4],hv[5],hv[6],hv[7]};
      *(float4*)&hT[fl][ib] = h0;
      *(float4*)&hT[fl][ib + 4] = h1;
    }
    __syncthreads();
    for (int f = 0; f < 128; ++f) {
      float4 ha = *(const float4*)&hT[f][ib];
      float4 hb = *(const float4*)&hT[f][ib + 4];
      float hv[8] = {ha.x,ha.y,ha.z,ha.w, hb.x,hb.y,hb.z,hb.w};
      const float* wp = w2e + (f0 + f) * D + l;
      float wv4[4] = {wp[0], wp[32], wp[64], wp[96]};
#pragma unroll
      for (int kk = 0; kk < 4; ++kk)
#pragma unroll
        for (int i = 0; i < 8; ++i) accO[kk][i] += wv4[kk] * hv[i];
    }
  }
  const float* b2e = b2 + e * D;
#pragma unroll
  for (int kk = 0; kk < 4; ++kk) {
    int o = l + kk * 32;
    float bb = b2e[o];
#pragma unroll
    for (int i = 0; i < 8; ++i) {
      int tok = toks[ib + i];
      if (tok >= 0)
        atomicAdd(&ff[tok * D + o], (accO[kk][i] + bb) * gws[ib + i]);
    }
  }
}

// ---------------- finalize: out = x1 + ff ; aux ----------------
__global__ void finalize_kernel(const float* __restrict__ x1, const float* __restrict__ ff,
                                const float* __restrict__ psum, const int* __restrict__ ecnt,
                                float* __restrict__ out) {
  int idx = blockIdx.x * 256 + threadIdx.x;
  float4 a = ((const float4*)x1)[idx];
  float4 b = ((const float4*)ff)[idx];
  float4 o = {a.x + b.x, a.y + b.y, a.z + b.z, a.w + b.w};
  ((float4*)out)[idx] = o;
  if (idx == 0) {
    float aux = 0.f;
    for (int e = 0; e < E; ++e)
      aux += ((float)ecnt[e] * (1.f / 16384.f)) * (psum[e] * (1.f / 8192.f));
    out[N * D] = 8.f * aux;
  }
}

extern "C" void kernel_launch(void* const* d_in, const int* in_sizes, int n_in,
                              void* d_out, int out_size, void* d_ws, size_t ws_size,
                              hipStream_t stream) {
  const float* x    = (const float*)d_in[0];
  const float* ln1g = (const float*)d_in[1];
  const float* ln1b = (const float*)d_in[2];
  const float* wq   = (const float*)d_in[3];
  const float* wk   = (const float*)d_in[4];
  const float* wv   = (const float*)d_in[5];
  const float* wp   = (const float*)d_in[6];
  const float* bp   = (const float*)d_in[7];
  const float* ln2g = (const float*)d_in[8];
  const float* ln2b = (const float*)d_in[9];
  const float* wg   = (const float*)d_in[10];
  const float* w1   = (const float*)d_in[11];
  const float* b1   = (const float*)d_in[12];
  const float* w2   = (const float*)d_in[13];
  const float* b2   = (const float*)d_in[14];
  float* out = (float*)d_out;
  float* ws = (float*)d_ws;
  const size_t M = 1u << 20;  // N*D floats
  float* xn   = ws + 0 * M;
  float* q    = ws + 1 * M;
  float* k    = ws + 2 * M;
  float* v    = ws + 3 * M;
  float* attn = ws + 4 * M;
  float* x1   = ws + 5 * M;
  float* xn2  = ws + 6 * M;
  float* ff   = ws + 7 * M;
  float* psum = ws + 8 * M;
  int*   ecnt = (int*)(ws + 8 * M + 8);
  int*   ltok = (int*)(ws + 8 * M + 16);
  float* lgw  = ws + 8 * M + 16 + E * N;

  hipMemsetAsync(ff, 0, (M + 16) * sizeof(float), stream);          // ff + psum + ecnt
  ln_kernel<<<N, 64, 0, stream>>>(x, ln1g, ln1b, xn);
  qkv_kernel<<<N / 16, 384, 0, stream>>>(xn, wq, wk, wv, q, k, v);
  attn_kernel<<<Bsz * H * (T / 64), 64, 0, stream>>>(q, k, v, attn);
  proj_kernel<<<N / 16, 128, 0, stream>>>(attn, wp, bp, x, x1);
  ln_kernel<<<N, 64, 0, stream>>>(x1, ln2g, ln2b, xn2);
  gate_kernel<<<N / 64, 64, 0, stream>>>(xn2, wg, psum, ecnt, ltok, lgw);
  moe_kernel<<<dim3(128, E), 256, 0, stream>>>(xn2, w1, b1, w2, b2, ecnt, ltok, lgw, ff);
  finalize_kernel<<<(N * D) / 1024, 256, 0, stream>>>(x1, ff, psum, ecnt, out);
}

// Round 2
// 442.178 us; speedup vs baseline: 3.3504x; 3.3504x over previous
//
#include <hip/hip_runtime.h>
#include <math.h>

#define Bsz 4
#define T 2048
#define D 128
#define H 8
#define HS 16
#define E 8
#define FF 512
#define N (Bsz*T)     // 8192
#define NQ (Bsz*H*T)  // 65536 query rows
#define EPS 1e-5f
#define SCALE 0.25f   // 1/sqrt(16)
#define SPLITS 8

__device__ __forceinline__ float wave_sum(float v) {
#pragma unroll
  for (int off = 32; off >= 1; off >>= 1) v += __shfl_xor(v, off);
  return v;
}

__device__ __forceinline__ float dot16(const float* qv, float4 a, float4 b, float4 c, float4 d) {
  return qv[0]*a.x + qv[1]*a.y + qv[2]*a.z + qv[3]*a.w
       + qv[4]*b.x + qv[5]*b.y + qv[6]*b.z + qv[7]*b.w
       + qv[8]*c.x + qv[9]*c.y + qv[10]*c.z + qv[11]*c.w
       + qv[12]*d.x + qv[13]*d.y + qv[14]*d.z + qv[15]*d.w;
}

__device__ __forceinline__ void fma16(float* acc, float p, float4 a, float4 b, float4 c, float4 d) {
  acc[0] += p*a.x;  acc[1] += p*a.y;  acc[2] += p*a.z;  acc[3] += p*a.w;
  acc[4] += p*b.x;  acc[5] += p*b.y;  acc[6] += p*b.z;  acc[7] += p*b.w;
  acc[8] += p*c.x;  acc[9] += p*c.y;  acc[10] += p*c.z; acc[11] += p*c.w;
  acc[12] += p*d.x; acc[13] += p*d.y; acc[14] += p*d.z; acc[15] += p*d.w;
}

// ---------------- LayerNorm: one wave per row of 128 ----------------
__global__ void ln_kernel(const float* __restrict__ x, const float* __restrict__ g,
                          const float* __restrict__ b, float* __restrict__ out) {
  int n = blockIdx.x;
  int tid = threadIdx.x;  // 64
  float2 v = ((const float2*)(x + n * D))[tid];
  float s  = wave_sum(v.x + v.y);
  float s2 = wave_sum(v.x * v.x + v.y * v.y);
  float m = s * (1.f / D);
  float var = s2 * (1.f / D) - m * m;
  float r = rsqrtf(var + EPS);
  float2 gg = ((const float2*)g)[tid];
  float2 bb = ((const float2*)b)[tid];
  float2 o;
  o.x = (v.x - m) * r * gg.x + bb.x;
  o.y = (v.y - m) * r * gg.y + bb.y;
  ((float2*)(out + n * D))[tid] = o;
}

// ---------------- QKV: 16 tokens/block, 384 threads ----------------
__global__ void qkv_kernel(const float* __restrict__ xn, const float* __restrict__ wq,
                           const float* __restrict__ wk, const float* __restrict__ wv,
                           float* __restrict__ q, float* __restrict__ k, float* __restrict__ v) {
  __shared__ float xs[D][20];
  int n0 = blockIdx.x * 16;
  int tid = threadIdx.x;
  for (int idx = tid; idx < 16 * D; idx += 384) {
    int t = idx >> 7, d = idx & 127;
    xs[d][t] = xn[(n0 + t) * D + d];
  }
  __syncthreads();
  int grp = tid / 128;        // 0=q 1=k 2=v (wave-uniform)
  int o = tid & 127;
  int h = o >> 4, e = o & 15;
  const float* w = (grp == 0 ? wq : (grp == 1 ? wk : wv)) + h * D * HS + e;
  float acc[16];
#pragma unroll
  for (int t = 0; t < 16; ++t) acc[t] = 0.f;
  for (int d = 0; d < D; ++d) {
    float wv_ = w[d * HS];
    float4 a0 = *(const float4*)&xs[d][0];
    float4 a1 = *(const float4*)&xs[d][4];
    float4 a2 = *(const float4*)&xs[d][8];
    float4 a3 = *(const float4*)&xs[d][12];
    float xv[16] = {a0.x,a0.y,a0.z,a0.w, a1.x,a1.y,a1.z,a1.w,
                    a2.x,a2.y,a2.z,a2.w, a3.x,a3.y,a3.z,a3.w};
#pragma unroll
    for (int t = 0; t < 16; ++t) acc[t] += wv_ * xv[t];
  }
  float* dst = (grp == 0 ? q : (grp == 1 ? k : v));
  int b_ = n0 / T, t0 = n0 % T;
#pragma unroll
  for (int t = 0; t < 16; ++t)
    dst[((b_ * H + h) * T + t0 + t) * HS + e] = acc[t];
}

// ---------------- attention partial: wave = 128 queries (2/lane), 256-key split ----------------
// partial layout: part[(s*18 + i)*NQ + n], n = bh*T + t; i: 0..15 acc, 16 m, 17 l
__global__ __launch_bounds__(64, 2) void attn_part(
    const float* __restrict__ q, const float* __restrict__ k,
    const float* __restrict__ v, float* __restrict__ part) {
  int bh = blockIdx.y;
  int qw = blockIdx.x >> 3;     // 0..15 (128 queries each)
  int s  = blockIdx.x & 7;      // split: keys [256s, 256s+256)
  int glo = 4 * s;
  int ghi = min(glo + 4, 2 * qw + 2);   // tiles g: keys [64g, 64g+64)
  if (glo >= ghi) return;
  int l = threadIdx.x;
  int t0 = qw * 128 + l;        // query 0; query 1 = t0+64
  __shared__ float4 ks[64][4];
  __shared__ float4 vs[64][4];
  float qa[16], qb[16];
  {
    const float4* qp0 = (const float4*)(q + (bh * T + t0) * HS);
    const float4* qp1 = (const float4*)(q + (bh * T + t0 + 64) * HS);
#pragma unroll
    for (int r = 0; r < 4; ++r) {
      float4 f0 = qp0[r], f1 = qp1[r];
      qa[4*r+0] = f0.x*SCALE; qa[4*r+1] = f0.y*SCALE; qa[4*r+2] = f0.z*SCALE; qa[4*r+3] = f0.w*SCALE;
      qb[4*r+0] = f1.x*SCALE; qb[4*r+1] = f1.y*SCALE; qb[4*r+2] = f1.z*SCALE; qb[4*r+3] = f1.w*SCALE;
    }
  }
  float acc0[16], acc1[16];
#pragma unroll
  for (int e = 0; e < 16; ++e) { acc0[e] = 0.f; acc1[e] = 0.f; }
  float m0 = -1e30f, m1 = -1e30f, l0 = 0.f, l1 = 0.f;
  for (int g = glo; g < ghi; ++g) {
    int k0 = g * 64;
    const float4* kp = (const float4*)(k + (bh * T + k0 + l) * HS);
    const float4* vp = (const float4*)(v + (bh * T + k0 + l) * HS);
    __syncthreads();
    ks[l][0] = kp[0]; ks[l][1] = kp[1]; ks[l][2] = kp[2]; ks[l][3] = kp[3];
    vs[l][0] = vp[0]; vs[l][1] = vp[1]; vs[l][2] = vp[2]; vs[l][3] = vp[3];
    __syncthreads();
#pragma unroll
    for (int jt = 0; jt < 4; ++jt) {
      float sc0[16], sc1[16];
      float sm0 = -1e30f, sm1 = -1e30f;
#pragma unroll
      for (int jj = 0; jj < 16; ++jj) {
        int j = jt * 16 + jj;
        float4 K0 = ks[j][0], K1 = ks[j][1], K2 = ks[j][2], K3 = ks[j][3];
        float d0 = dot16(qa, K0, K1, K2, K3);
        float d1 = dot16(qb, K0, K1, K2, K3);
        int key = k0 + j;
        d0 = (key <= t0)      ? d0 : -1e30f;
        d1 = (key <= t0 + 64) ? d1 : -1e30f;
        sc0[jj] = d0; sm0 = fmaxf(sm0, d0);
        sc1[jj] = d1; sm1 = fmaxf(sm1, d1);
      }
      float mn0 = fmaxf(m0, sm0); float c0 = __expf(m0 - mn0); m0 = mn0; l0 *= c0;
      float mn1 = fmaxf(m1, sm1); float c1 = __expf(m1 - mn1); m1 = mn1; l1 *= c1;
#pragma unroll
      for (int e = 0; e < 16; ++e) { acc0[e] *= c0; acc1[e] *= c1; }
#pragma unroll
      for (int jj = 0; jj < 16; ++jj) {
        int j = jt * 16 + jj;
        float p0 = __expf(sc0[jj] - m0);
        float p1 = __expf(sc1[jj] - m1);
        l0 += p0; l1 += p1;
        float4 V0 = vs[j][0], V1 = vs[j][1], V2 = vs[j][2], V3 = vs[j][3];
        fma16(acc0, p0, V0, V1, V2, V3);
        fma16(acc1, p1, V0, V1, V2, V3);
      }
    }
  }
  int n0 = bh * T + t0;
  float* pb = part + (size_t)s * 18 * NQ;
#pragma unroll
  for (int e = 0; e < 16; ++e) {
    pb[e * NQ + n0]      = acc0[e];
    pb[e * NQ + n0 + 64] = acc1[e];
  }
  pb[16 * NQ + n0]      = m0; pb[17 * NQ + n0]      = l0;
  pb[16 * NQ + n0 + 64] = m1; pb[17 * NQ + n0 + 64] = l1;
}

// ---------------- attention combine: lane = one query row ----------------
__global__ void attn_comb(const float* __restrict__ part, float* __restrict__ ao) {
  int n = blockIdx.x * 64 + threadIdx.x;   // 0..NQ-1
  int t = n & (T - 1);
  int ns = (t >> 8) + 1;                   // splits with any keys <= t
  float m = -1e30f;
  for (int s = 0; s < ns; ++s)
    m = fmaxf(m, part[(s * 18 + 16) * NQ + n]);
  float acc[16];
#pragma unroll
  for (int e = 0; e < 16; ++e) acc[e] = 0.f;
  float L = 0.f;
  for (int s = 0; s < ns; ++s) {
    float w = __expf(part[(s * 18 + 16) * NQ + n] - m);
    L += w * part[(s * 18 + 17) * NQ + n];
#pragma unroll
    for (int e = 0; e < 16; ++e)
      acc[e] += w * part[(s * 18 + e) * NQ + n];
  }
  float inv = 1.f / L;
  int bh = n >> 11, b = bh >> 3, h = bh & 7;
  float* op = ao + ((size_t)(b * T + t) * D) + h * HS;
#pragma unroll
  for (int r = 0; r < 4; ++r) {
    float4 o4 = {acc[4*r]*inv, acc[4*r+1]*inv, acc[4*r+2]*inv, acc[4*r+3]*inv};
    ((float4*)op)[r] = o4;
  }
}

// ---------------- proj + bias + residual ----------------
__global__ void proj_kernel(const float* __restrict__ attn, const float* __restrict__ wp,
                            const float* __restrict__ bp, const float* __restrict__ x,
                            float* __restrict__ x1) {
  __shared__ float as_[D][20];
  int n0 = blockIdx.x * 16;
  int tid = threadIdx.x;  // 128
  for (int idx = tid; idx < 16 * D; idx += 128) {
    int t = idx >> 7, d = idx & 127;
    as_[d][t] = attn[(n0 + t) * D + d];
  }
  __syncthreads();
  float acc[16];
#pragma unroll
  for (int t = 0; t < 16; ++t) acc[t] = 0.f;
  for (int d = 0; d < D; ++d) {
    float w = wp[d * D + tid];
    float4 a0 = *(const float4*)&as_[d][0];
    float4 a1 = *(const float4*)&as_[d][4];
    float4 a2 = *(const float4*)&as_[d][8];
    float4 a3 = *(const float4*)&as_[d][12];
    float xv[16] = {a0.x,a0.y,a0.z,a0.w, a1.x,a1.y,a1.z,a1.w,
                    a2.x,a2.y,a2.z,a2.w, a3.x,a3.y,a3.z,a3.w};
#pragma unroll
    for (int t = 0; t < 16; ++t) acc[t] += w * xv[t];
  }
  float bb = bp[tid];
#pragma unroll
  for (int t = 0; t < 16; ++t) {
    int idx = (n0 + t) * D + tid;
    x1[idx] = x[idx] + acc[t] + bb;
  }
}

// ---------------- gate: softmax(8), top-2, bucketing + slot index ----------------
__global__ void gate_kernel(const float* __restrict__ xn2, const float* __restrict__ wg,
                            float* __restrict__ psum, int* __restrict__ ecnt,
                            int* __restrict__ ltok, int* __restrict__ sidx,
                            float* __restrict__ gwn) {
  int lane = threadIdx.x;  // 64
  int n = blockIdx.x * 64 + lane;
  const float4* xr = (const float4*)(xn2 + (size_t)n * D);
  float lg[E];
#pragma unroll
  for (int e = 0; e < E; ++e) lg[e] = 0.f;
  for (int dq = 0; dq < 32; ++dq) {
    float4 xv = xr[dq];
    int d = dq * 4;
#pragma unroll
    for (int e = 0; e < E; ++e)
      lg[e] += xv.x * wg[d*E + e] + xv.y * wg[(d+1)*E + e]
             + xv.z * wg[(d+2)*E + e] + xv.w * wg[(d+3)*E + e];
  }
  float mx = lg[0];
#pragma unroll
  for (int e = 1; e < E; ++e) mx = fmaxf(mx, lg[e]);
  float p[E]; float s = 0.f;
#pragma unroll
  for (int e = 0; e < E; ++e) { p[e] = __expf(lg[e] - mx); s += p[e]; }
  float invs = 1.f / s;
#pragma unroll
  for (int e = 0; e < E; ++e) p[e] *= invs;
#pragma unroll
  for (int e = 0; e < E; ++e) {
    float ve = wave_sum(p[e]);
    if (lane == 0) atomicAdd(&psum[e], ve);
  }
  int i1 = 0; float p1 = p[0];
#pragma unroll
  for (int e = 1; e < E; ++e) if (p[e] > p1) { p1 = p[e]; i1 = e; }
  int i2 = (i1 == 0) ? 1 : 0; float p2 = p[i2];
#pragma unroll
  for (int e = 0; e < E; ++e) if (e != i1 && p[e] > p2) { p2 = p[e]; i2 = e; }
  float gden = 1.f / (p1 + p2);
  for (int kk = 0; kk < 2; ++kk) {
    int ei = kk ? i2 : i1;
    float g = (kk ? p2 : p1) * gden;
#pragma unroll
    for (int e = 0; e < E; ++e) {
      unsigned long long msk = __ballot(ei == e);
      if (msk == 0) continue;
      int cnt = __popcll(msk);
      int leader = __ffsll(msk) - 1;
      int base = 0;
      if (lane == leader) base = atomicAdd(&ecnt[e], cnt);
      base = __shfl(base, leader);
      if (ei == e) {
        int off = __popcll(msk & ((1ULL << lane) - 1ULL));
        int pos = base + off;
        ltok[e * N + pos] = n;
        sidx[n * 2 + kk] = e * N + pos;
        gwn[n * 2 + kk] = g;
      }
    }
  }
}

// ---------------- grouped expert FFN: 64 tokens x 1 expert per block ----------------
__global__ __launch_bounds__(256) void moe_kernel(
    const float* __restrict__ xn2, const float* __restrict__ w1,
    const float* __restrict__ b1, const float* __restrict__ w2,
    const float* __restrict__ b2, const int* __restrict__ ecnt,
    const int* __restrict__ ltok, float* __restrict__ eo) {
  int e = blockIdx.y;
  int cnt = ecnt[e];
  int t0 = blockIdx.x * 64;
  if (t0 >= cnt) return;
  int nt = min(64, cnt - t0);
  __shared__ float xT[D][68];
  __shared__ float hT[128][68];
  __shared__ int toks[64];
  int tid = threadIdx.x;
  if (tid < 64)
    toks[tid] = (tid < nt) ? ltok[e * N + t0 + tid] : -1;
  __syncthreads();
  {
    int i = tid >> 2, c = tid & 3;
    int tok = toks[i];
    const float* src = xn2 + (size_t)(tok < 0 ? 0 : tok) * D;
    for (int j = 0; j < 32; ++j) {
      int d = c * 32 + j;
      xT[d][i] = (tok >= 0) ? src[d] : 0.f;
    }
  }
  __syncthreads();
  int l = tid & 31;
  int ib = (tid >> 5) * 8;
  float accO[4][8];
#pragma unroll
  for (int kk = 0; kk < 4; ++kk)
#pragma unroll
    for (int i = 0; i < 8; ++i) accO[kk][i] = 0.f;
  const float* w1e = w1 + (size_t)e * D * FF;
  const float* w2e = w2 + (size_t)e * FF * D;
  const float* b1e = b1 + e * FF;
  for (int fc = 0; fc < 4; ++fc) {
    int f0 = fc * 128;
    float accH[4][8];
#pragma unroll
    for (int kk = 0; kk < 4; ++kk)
#pragma unroll
      for (int i = 0; i < 8; ++i) accH[kk][i] = 0.f;
    for (int d = 0; d < D; ++d) {
      float4 xa = *(const float4*)&xT[d][ib];
      float4 xb = *(const float4*)&xT[d][ib + 4];
      float xv[8] = {xa.x,xa.y,xa.z,xa.w, xb.x,xb.y,xb.z,xb.w};
      const float* wp = w1e + (size_t)d * FF + f0 + l;
      float wv4[4] = {wp[0], wp[32], wp[64], wp[96]};
#pragma unroll
      for (int kk = 0; kk < 4; ++kk)
#pragma unroll
        for (int i = 0; i < 8; ++i) accH[kk][i] += wv4[kk] * xv[i];
    }
    __syncthreads();
#pragma unroll
    for (int kk = 0; kk < 4; ++kk) {
      int fl = l + kk * 32;
      float bb = b1e[f0 + fl];
      float hv[8];
#pragma unroll
      for (int i = 0; i < 8; ++i) {
        float z = accH[kk][i] + bb;
        hv[i] = 0.5f * z * (1.f + erff(z * 0.70710678f));
      }
      float4 h0 = {hv[0],hv[1],hv[2],hv[3]};
      float4 h1 = {hv[4],hv[5],hv[6],hv[7]};
      *(float4*)&hT[fl][ib] = h0;
      *(float4*)&hT[fl][ib + 4] = h1;
    }
    __syncthreads();
    for (int f = 0; f < 128; ++f) {
      float4 ha = *(const float4*)&hT[f][ib];
      float4 hb = *(const float4*)&hT[f][ib + 4];
      float hv[8] = {ha.x,ha.y,ha.z,ha.w, hb.x,hb.y,hb.z,hb.w};
      const float* wp = w2e + (size_t)(f0 + f) * D + l;
      float wv4[4] = {wp[0], wp[32], wp[64], wp[96]};
#pragma unroll
      for (int kk = 0; kk < 4; ++kk)
#pragma unroll
        for (int i = 0; i < 8; ++i) accO[kk][i] += wv4[kk] * hv[i];
    }
  }
  const float* b2e = b2 + e * D;
  float* eop = eo + ((size_t)(e * N + t0)) * 128;
#pragma unroll
  for (int kk = 0; kk < 4; ++kk) {
    int o = l + kk * 32;
    float bb = b2e[o];
#pragma unroll
    for (int i = 0; i < 8; ++i)
      eop[(size_t)(ib + i) * 128 + o] = accO[kk][i] + bb;
  }
}

// ---------------- finalize: out = x1 + g0*eo[i0] + g1*eo[i1]; aux ----------------
__global__ void finalize_kernel(const float* __restrict__ x1, const float* __restrict__ eo,
                                const int* __restrict__ sidx, const float* __restrict__ gwn,
                                const float* __restrict__ psum, const int* __restrict__ ecnt,
                                float* __restrict__ out) {
  int idx = blockIdx.x * 256 + threadIdx.x;   // float4 index, N*D/4 total
  int n = idx >> 5, d4 = idx & 31;
  int i0 = sidx[2*n], i1 = sidx[2*n+1];
  float g0 = gwn[2*n], g1 = gwn[2*n+1];
  float4 a = ((const float4*)x1)[idx];
  float4 u = ((const float4*)eo)[(size_t)i0 * 32 + d4];
  float4 w = ((const float4*)eo)[(size_t)i1 * 32 + d4];
  float4 o = {a.x + g0*u.x + g1*w.x, a.y + g0*u.y + g1*w.y,
              a.z + g0*u.z + g1*w.z, a.w + g0*u.w + g1*w.w};
  ((float4*)out)[idx] = o;
  if (idx == 0) {
    float aux = 0.f;
    for (int e = 0; e < E; ++e)
      aux += ((float)ecnt[e] * (1.f / 16384.f)) * (psum[e] * (1.f / 8192.f));
    out[N * D] = 8.f * aux;
  }
}

extern "C" void kernel_launch(void* const* d_in, const int* in_sizes, int n_in,
                              void* d_out, int out_size, void* d_ws, size_t ws_size,
                              hipStream_t stream) {
  const float* x    = (const float*)d_in[0];
  const float* ln1g = (const float*)d_in[1];
  const float* ln1b = (const float*)d_in[2];
  const float* wq   = (const float*)d_in[3];
  const float* wk   = (const float*)d_in[4];
  const float* wv   = (const float*)d_in[5];
  const float* wp   = (const float*)d_in[6];
  const float* bp   = (const float*)d_in[7];
  const float* ln2g = (const float*)d_in[8];
  const float* ln2b = (const float*)d_in[9];
  const float* wg   = (const float*)d_in[10];
  const float* w1   = (const float*)d_in[11];
  const float* b1   = (const float*)d_in[12];
  const float* w2   = (const float*)d_in[13];
  const float* b2   = (const float*)d_in[14];
  float* out = (float*)d_out;
  float* ws = (float*)d_ws;
  const size_t M = 1u << 20;  // 1M floats
  // slot A: xn -> attnout ; slot B: q -> x1 ; slot C: k -> xn2 ; slot V: v
  float* A  = ws;
  float* Bq = ws + 1 * M;
  float* Ck = ws + 2 * M;
  float* Vv = ws + 3 * M;
  float* part = ws + 4 * M;                  // 18*8*NQ = 9,437,184 floats
  float* eo   = ws + 4 * M;                  // reuses dead partials; 8,388,608 floats
  size_t G0 = 4 * M + (size_t)18 * SPLITS * NQ;  // 13,631,488
  int*   ltok = (int*)(ws + G0);             // 65536
  int*   sidx = (int*)(ws + G0 + 65536);     // 16384
  float* gwn  = ws + G0 + 81920;             // 16384
  float* psum = ws + G0 + 98304;             // 8
  int*   ecnt = (int*)(ws + G0 + 98312);     // 8

  hipMemsetAsync(psum, 0, 64, stream);       // psum + ecnt
  ln_kernel<<<N, 64, 0, stream>>>(x, ln1g, ln1b, A);
  qkv_kernel<<<N / 16, 384, 0, stream>>>(A, wq, wk, wv, Bq, Ck, Vv);
  attn_part<<<dim3(16 * SPLITS, Bsz * H), 64, 0, stream>>>(Bq, Ck, Vv, part);
  attn_comb<<<NQ / 64, 64, 0, stream>>>(part, A);
  proj_kernel<<<N / 16, 128, 0, stream>>>(A, wp, bp, x, Bq);
  ln_kernel<<<N, 64, 0, stream>>>(Bq, ln2g, ln2b, Ck);
  gate_kernel<<<N / 64, 64, 0, stream>>>(Ck, wg, psum, ecnt, ltok, sidx, gwn);
  moe_kernel<<<dim3(128, E), 256, 0, stream>>>(Ck, w1, b1, w2, b2, ecnt, ltok, eo);
  finalize_kernel<<<(N * D / 4) / 256, 256, 0, stream>>>(Bq, eo, sidx, gwn, psum, ecnt, out);
}

// Round 3
// 289.295 us; speedup vs baseline: 5.1210x; 1.5285x over previous
//
#include <hip/hip_runtime.h>
#include <math.h>

#define Bsz 4
#define T 2048
#define D 128
#define H 8
#define HS 16
#define E 8
#define FF 512
#define N (Bsz*T)     // 8192
#define NQ (Bsz*H*T)  // 65536 query rows
#define EPS 1e-5f
#define SCALE 0.25f   // 1/sqrt(16)
#define SPLITS 8

typedef _Float16 h4 __attribute__((ext_vector_type(4)));
typedef float f4 __attribute__((ext_vector_type(4)));
#define MFMA16 __builtin_amdgcn_mfma_f32_16x16x16f16

__device__ __forceinline__ float wave_sum(float v) {
#pragma unroll
  for (int off = 32; off >= 1; off >>= 1) v += __shfl_xor(v, off);
  return v;
}

// ---------------- LayerNorm: one wave per row of 128 ----------------
__global__ void ln_kernel(const float* __restrict__ x, const float* __restrict__ g,
                          const float* __restrict__ b, float* __restrict__ out) {
  int n = blockIdx.x;
  int tid = threadIdx.x;  // 64
  float2 v = ((const float2*)(x + n * D))[tid];
  float s  = wave_sum(v.x + v.y);
  float s2 = wave_sum(v.x * v.x + v.y * v.y);
  float m = s * (1.f / D);
  float var = s2 * (1.f / D) - m * m;
  float r = rsqrtf(var + EPS);
  float2 gg = ((const float2*)g)[tid];
  float2 bb = ((const float2*)b)[tid];
  float2 o;
  o.x = (v.x - m) * r * gg.x + bb.x;
  o.y = (v.y - m) * r * gg.y + bb.y;
  ((float2*)(out + n * D))[tid] = o;
}

// ---------------- QKV: 16 tokens/block, 384 threads; f16 outputs ----------------
__global__ void qkv_kernel(const float* __restrict__ xn, const float* __restrict__ wq,
                           const float* __restrict__ wk, const float* __restrict__ wv,
                           _Float16* __restrict__ qh, _Float16* __restrict__ kh,
                           _Float16* __restrict__ vTh) {
  __shared__ float xs[D][20];
  int n0 = blockIdx.x * 16;
  int tid = threadIdx.x;
  for (int idx = tid; idx < 16 * D; idx += 384) {
    int t = idx >> 7, d = idx & 127;
    xs[d][t] = xn[(n0 + t) * D + d];
  }
  __syncthreads();
  int grp = tid / 128;        // 0=q 1=k 2=v (wave-uniform)
  int o = tid & 127;
  int h = o >> 4, e = o & 15;
  const float* w = (grp == 0 ? wq : (grp == 1 ? wk : wv)) + h * D * HS + e;
  float acc[16];
#pragma unroll
  for (int t = 0; t < 16; ++t) acc[t] = 0.f;
  for (int d = 0; d < D; ++d) {
    float wv_ = w[d * HS];
    float4 a0 = *(const float4*)&xs[d][0];
    float4 a1 = *(const float4*)&xs[d][4];
    float4 a2 = *(const float4*)&xs[d][8];
    float4 a3 = *(const float4*)&xs[d][12];
    float xv[16] = {a0.x,a0.y,a0.z,a0.w, a1.x,a1.y,a1.z,a1.w,
                    a2.x,a2.y,a2.z,a2.w, a3.x,a3.y,a3.z,a3.w};
#pragma unroll
    for (int t = 0; t < 16; ++t) acc[t] += wv_ * xv[t];
  }
  int b_ = n0 / T, t0 = n0 % T;
  if (grp == 0) {
    _Float16* dq = qh + ((size_t)(b_ * H + h) * T + t0) * 16 + e;
#pragma unroll
    for (int t = 0; t < 16; ++t) dq[t * 16] = (_Float16)(acc[t] * SCALE);
  } else if (grp == 1) {
    _Float16* dk = kh + ((size_t)(b_ * H + h) * T + t0) * 16 + e;
#pragma unroll
    for (int t = 0; t < 16; ++t) dk[t * 16] = (_Float16)acc[t];
  } else {
    _Float16* dv = vTh + ((size_t)(b_ * H + h) * 16 + e) * T + t0;
#pragma unroll
    for (int t = 0; t < 16; ++t) dv[t] = (_Float16)acc[t];
  }
}

// ---------------- MFMA flash attention partial ----------------
// wave = 64 queries x 256-key split; S^T = mfma(K,Q); O^T = mfma(V^T,P^T)
// partial layout: part[(s*18 + i)*NQ + n]; i: 0..15 acc(hs), 16 m, 17 l
__global__ __launch_bounds__(64) void attn_mfma(
    const _Float16* __restrict__ q, const _Float16* __restrict__ k,
    const _Float16* __restrict__ vT, float* __restrict__ part) {
  int bh = blockIdx.y;
  int qt = blockIdx.x >> 3;     // 0..31 (64 queries)
  int s  = blockIdx.x & 7;      // split: keys [256s, 256s+256)
  int glo = 4 * s;
  int ghi = min(glo + 4, qt + 1);
  if (glo >= ghi) return;
  int l = threadIdx.x;
  int lg = l >> 4, lr = l & 15;
  int q0 = qt * 64;
  // Q B-frags: lane holds Q[q0+16nt+lr][4lg..4lg+3]
  const h4* qp = (const h4*)(q + ((size_t)bh * T + q0 + lr) * 16 + 4 * lg);
  h4 qf[4];
#pragma unroll
  for (int nt = 0; nt < 4; ++nt) qf[nt] = qp[nt * 64];
  f4 o0 = {0.f,0.f,0.f,0.f}, o1 = o0, o2 = o0, o3 = o0;
  float m0 = -1e30f, m1 = -1e30f, m2 = -1e30f, m3 = -1e30f;
  float l0 = 0.f, l1 = 0.f, l2 = 0.f, l3 = 0.f;
  for (int g = glo; g < ghi; ++g) {
    int k0g = g * 64;
    const h4* kp = (const h4*)(k + ((size_t)bh * T + k0g + lr) * 16 + 4 * lg);
    h4 kf[4];
#pragma unroll
    for (int mt = 0; mt < 4; ++mt) kf[mt] = kp[mt * 64];
    const h4* vp = (const h4*)(vT + ((size_t)bh * 16 + lr) * T + k0g + 4 * lg);
    h4 vf[4];
#pragma unroll
    for (int mt = 0; mt < 4; ++mt) vf[mt] = vp[mt * 4];
    f4 z = {0.f,0.f,0.f,0.f};
    f4 sc[4][4];
#pragma unroll
    for (int mt = 0; mt < 4; ++mt)
#pragma unroll
      for (int nt = 0; nt < 4; ++nt)
        sc[mt][nt] = MFMA16(kf[mt], qf[nt], z, 0, 0, 0);
    if (g == qt) {  // diagonal tile: mask key > query
#pragma unroll
      for (int mt = 0; mt < 4; ++mt)
#pragma unroll
        for (int nt = 0; nt < 4; ++nt) {
          int kb = 16 * mt + 4 * lg, qb = 16 * nt + lr;
          if (kb + 0 > qb) sc[mt][nt].x = -1e30f;
          if (kb + 1 > qb) sc[mt][nt].y = -1e30f;
          if (kb + 2 > qb) sc[mt][nt].z = -1e30f;
          if (kb + 3 > qb) sc[mt][nt].w = -1e30f;
        }
    }
#define PROC(NT, M, L, O) do { \
    float tm = -1e30f; \
    _Pragma("unroll") for (int mt = 0; mt < 4; ++mt) { \
      f4 a = sc[mt][NT]; \
      tm = fmaxf(tm, fmaxf(fmaxf(a.x, a.y), fmaxf(a.z, a.w))); } \
    tm = fmaxf(tm, __shfl_xor(tm, 16)); \
    tm = fmaxf(tm, __shfl_xor(tm, 32)); \
    float mn = fmaxf(M, tm); \
    float c = __expf(M - mn); M = mn; L *= c; \
    O.x *= c; O.y *= c; O.z *= c; O.w *= c; \
    float sum = 0.f; h4 pf[4]; \
    _Pragma("unroll") for (int mt = 0; mt < 4; ++mt) { \
      f4 a = sc[mt][NT]; h4 p; float ex; \
      ex = __expf(a.x - mn); sum += ex; p.x = (_Float16)ex; \
      ex = __expf(a.y - mn); sum += ex; p.y = (_Float16)ex; \
      ex = __expf(a.z - mn); sum += ex; p.z = (_Float16)ex; \
      ex = __expf(a.w - mn); sum += ex; p.w = (_Float16)ex; \
      pf[mt] = p; } \
    sum += __shfl_xor(sum, 16); sum += __shfl_xor(sum, 32); L += sum; \
    _Pragma("unroll") for (int mt = 0; mt < 4; ++mt) \
      O = MFMA16(vf[mt], pf[mt], O, 0, 0, 0); \
  } while (0)
    PROC(0, m0, l0, o0);
    PROC(1, m1, l1, o1);
    PROC(2, m2, l2, o2);
    PROC(3, m3, l3, o3);
#undef PROC
  }
  float* pb = part + (size_t)s * 18 * NQ;
  int nbase = bh * T + q0 + lr;
#define WR(NT, M, L, O) do { int n = nbase + 16 * NT; \
    pb[(4 * lg + 0) * NQ + n] = O.x; pb[(4 * lg + 1) * NQ + n] = O.y; \
    pb[(4 * lg + 2) * NQ + n] = O.z; pb[(4 * lg + 3) * NQ + n] = O.w; \
    if (lg == 0) { pb[16 * NQ + n] = M; pb[17 * NQ + n] = L; } \
  } while (0)
  WR(0, m0, l0, o0);
  WR(1, m1, l1, o1);
  WR(2, m2, l2, o2);
  WR(3, m3, l3, o3);
#undef WR
}

// ---------------- attention combine: lane = one query row ----------------
__global__ void attn_comb(const float* __restrict__ part, float* __restrict__ ao) {
  int n = blockIdx.x * 64 + threadIdx.x;   // 0..NQ-1
  int t = n & (T - 1);
  int ns = (t >> 8) + 1;                   // splits with any keys <= t
  float m = -1e30f;
  for (int s = 0; s < ns; ++s)
    m = fmaxf(m, part[(s * 18 + 16) * NQ + n]);
  float acc[16];
#pragma unroll
  for (int e = 0; e < 16; ++e) acc[e] = 0.f;
  float L = 0.f;
  for (int s = 0; s < ns; ++s) {
    float w = __expf(part[(s * 18 + 16) * NQ + n] - m);
    L += w * part[(s * 18 + 17) * NQ + n];
#pragma unroll
    for (int e = 0; e < 16; ++e)
      acc[e] += w * part[(s * 18 + e) * NQ + n];
  }
  float inv = 1.f / L;
  int bh = n >> 11, b = bh >> 3, h = bh & 7;
  float* op = ao + ((size_t)(b * T + t) * D) + h * HS;
#pragma unroll
  for (int r = 0; r < 4; ++r) {
    float4 o4 = {acc[4*r]*inv, acc[4*r+1]*inv, acc[4*r+2]*inv, acc[4*r+3]*inv};
    ((float4*)op)[r] = o4;
  }
}

// ---------------- proj + bias + residual ----------------
__global__ void proj_kernel(const float* __restrict__ attn, const float* __restrict__ wp,
                            const float* __restrict__ bp, const float* __restrict__ x,
                            float* __restrict__ x1) {
  __shared__ float as_[D][20];
  int n0 = blockIdx.x * 16;
  int tid = threadIdx.x;  // 128
  for (int idx = tid; idx < 16 * D; idx += 128) {
    int t = idx >> 7, d = idx & 127;
    as_[d][t] = attn[(n0 + t) * D + d];
  }
  __syncthreads();
  float acc[16];
#pragma unroll
  for (int t = 0; t < 16; ++t) acc[t] = 0.f;
  for (int d = 0; d < D; ++d) {
    float w = wp[d * D + tid];
    float4 a0 = *(const float4*)&as_[d][0];
    float4 a1 = *(const float4*)&as_[d][4];
    float4 a2 = *(const float4*)&as_[d][8];
    float4 a3 = *(const float4*)&as_[d][12];
    float xv[16] = {a0.x,a0.y,a0.z,a0.w, a1.x,a1.y,a1.z,a1.w,
                    a2.x,a2.y,a2.z,a2.w, a3.x,a3.y,a3.z,a3.w};
#pragma unroll
    for (int t = 0; t < 16; ++t) acc[t] += w * xv[t];
  }
  float bb = bp[tid];
#pragma unroll
  for (int t = 0; t < 16; ++t) {
    int idx = (n0 + t) * D + tid;
    x1[idx] = x[idx] + acc[t] + bb;
  }
}

// ---------------- gate: softmax(8), top-2, bucketing + slot index ----------------
__global__ void gate_kernel(const float* __restrict__ xn2, const float* __restrict__ wg,
                            float* __restrict__ psum, int* __restrict__ ecnt,
                            int* __restrict__ ltok, int* __restrict__ sidx,
                            float* __restrict__ gwn) {
  int lane = threadIdx.x;  // 64
  int n = blockIdx.x * 64 + lane;
  const float4* xr = (const float4*)(xn2 + (size_t)n * D);
  float lg[E];
#pragma unroll
  for (int e = 0; e < E; ++e) lg[e] = 0.f;
  for (int dq = 0; dq < 32; ++dq) {
    float4 xv = xr[dq];
    int d = dq * 4;
#pragma unroll
    for (int e = 0; e < E; ++e)
      lg[e] += xv.x * wg[d*E + e] + xv.y * wg[(d+1)*E + e]
             + xv.z * wg[(d+2)*E + e] + xv.w * wg[(d+3)*E + e];
  }
  float mx = lg[0];
#pragma unroll
  for (int e = 1; e < E; ++e) mx = fmaxf(mx, lg[e]);
  float p[E]; float s = 0.f;
#pragma unroll
  for (int e = 0; e < E; ++e) { p[e] = __expf(lg[e] - mx); s += p[e]; }
  float invs = 1.f / s;
#pragma unroll
  for (int e = 0; e < E; ++e) p[e] *= invs;
#pragma unroll
  for (int e = 0; e < E; ++e) {
    float ve = wave_sum(p[e]);
    if (lane == 0) atomicAdd(&psum[e], ve);
  }
  int i1 = 0; float p1 = p[0];
#pragma unroll
  for (int e = 1; e < E; ++e) if (p[e] > p1) { p1 = p[e]; i1 = e; }
  int i2 = (i1 == 0) ? 1 : 0; float p2 = p[i2];
#pragma unroll
  for (int e = 0; e < E; ++e) if (e != i1 && p[e] > p2) { p2 = p[e]; i2 = e; }
  float gden = 1.f / (p1 + p2);
  for (int kk = 0; kk < 2; ++kk) {
    int ei = kk ? i2 : i1;
    float g = (kk ? p2 : p1) * gden;
#pragma unroll
    for (int e = 0; e < E; ++e) {
      unsigned long long msk = __ballot(ei == e);
      if (msk == 0) continue;
      int cnt = __popcll(msk);
      int leader = __ffsll(msk) - 1;
      int base = 0;
      if (lane == leader) base = atomicAdd(&ecnt[e], cnt);
      base = __shfl(base, leader);
      if (ei == e) {
        int off = __popcll(msk & ((1ULL << lane) - 1ULL));
        int pos = base + off;
        ltok[e * N + pos] = n;
        sidx[n * 2 + kk] = e * N + pos;
        gwn[n * 2 + kk] = g;
      }
    }
  }
}

// ---------------- grouped expert FFN: 64 tokens x 1 expert per block ----------------
__global__ __launch_bounds__(256) void moe_kernel(
    const float* __restrict__ xn2, const float* __restrict__ w1,
    const float* __restrict__ b1, const float* __restrict__ w2,
    const float* __restrict__ b2, const int* __restrict__ ecnt,
    const int* __restrict__ ltok, float* __restrict__ eo) {
  int e = blockIdx.y;
  int cnt = ecnt[e];
  int t0 = blockIdx.x * 64;
  if (t0 >= cnt) return;
  int nt = min(64, cnt - t0);
  __shared__ float xT[D][68];
  __shared__ float hT[128][68];
  __shared__ int toks[64];
  int tid = threadIdx.x;
  if (tid < 64)
    toks[tid] = (tid < nt) ? ltok[e * N + t0 + tid] : -1;
  __syncthreads();
  {
    int i = tid >> 2, c = tid & 3;
    int tok = toks[i];
    const float* src = xn2 + (size_t)(tok < 0 ? 0 : tok) * D;
    for (int j = 0; j < 32; ++j) {
      int d = c * 32 + j;
      xT[d][i] = (tok >= 0) ? src[d] : 0.f;
    }
  }
  __syncthreads();
  int l = tid & 31;
  int ib = (tid >> 5) * 8;
  float accO[4][8];
#pragma unroll
  for (int kk = 0; kk < 4; ++kk)
#pragma unroll
    for (int i = 0; i < 8; ++i) accO[kk][i] = 0.f;
  const float* w1e = w1 + (size_t)e * D * FF;
  const float* w2e = w2 + (size_t)e * FF * D;
  const float* b1e = b1 + e * FF;
  for (int fc = 0; fc < 4; ++fc) {
    int f0 = fc * 128;
    float accH[4][8];
#pragma unroll
    for (int kk = 0; kk < 4; ++kk)
#pragma unroll
      for (int i = 0; i < 8; ++i) accH[kk][i] = 0.f;
    for (int d = 0; d < D; ++d) {
      float4 xa = *(const float4*)&xT[d][ib];
      float4 xb = *(const float4*)&xT[d][ib + 4];
      float xv[8] = {xa.x,xa.y,xa.z,xa.w, xb.x,xb.y,xb.z,xb.w};
      const float* wp = w1e + (size_t)d * FF + f0 + l;
      float wv4[4] = {wp[0], wp[32], wp[64], wp[96]};
#pragma unroll
      for (int kk = 0; kk < 4; ++kk)
#pragma unroll
        for (int i = 0; i < 8; ++i) accH[kk][i] += wv4[kk] * xv[i];
    }
    __syncthreads();
#pragma unroll
    for (int kk = 0; kk < 4; ++kk) {
      int fl = l + kk * 32;
      float bb = b1e[f0 + fl];
      float hv[8];
#pragma unroll
      for (int i = 0; i < 8; ++i) {
        float z = accH[kk][i] + bb;
        hv[i] = 0.5f * z * (1.f + erff(z * 0.70710678f));
      }
      float4 h0 = {hv[0],hv[1],hv[2],hv[3]};
      float4 h1 = {hv[4],hv[5],hv[6],hv[7]};
      *(float4*)&hT[fl][ib] = h0;
      *(float4*)&hT[fl][ib + 4] = h1;
    }
    __syncthreads();
    for (int f = 0; f < 128; ++f) {
      float4 ha = *(const float4*)&hT[f][ib];
      float4 hb = *(const float4*)&hT[f][ib + 4];
      float hv[8] = {ha.x,ha.y,ha.z,ha.w, hb.x,hb.y,hb.z,hb.w};
      const float* wp = w2e + (size_t)(f0 + f) * D + l;
      float wv4[4] = {wp[0], wp[32], wp[64], wp[96]};
#pragma unroll
      for (int kk = 0; kk < 4; ++kk)
#pragma unroll
        for (int i = 0; i < 8; ++i) accO[kk][i] += wv4[kk] * hv[i];
    }
  }
  const float* b2e = b2 + e * D;
  float* eop = eo + ((size_t)(e * N + t0)) * 128;
#pragma unroll
  for (int kk = 0; kk < 4; ++kk) {
    int o = l + kk * 32;
    float bb = b2e[o];
#pragma unroll
    for (int i = 0; i < 8; ++i)
      eop[(size_t)(ib + i) * 128 + o] = accO[kk][i] + bb;
  }
}

// ---------------- finalize: out = x1 + g0*eo[i0] + g1*eo[i1]; aux ----------------
__global__ void finalize_kernel(const float* __restrict__ x1, const float* __restrict__ eo,
                                const int* __restrict__ sidx, const float* __restrict__ gwn,
                                const float* __restrict__ psum, const int* __restrict__ ecnt,
                                float* __restrict__ out) {
  int idx = blockIdx.x * 256 + threadIdx.x;   // float4 index, N*D/4 total
  int n = idx >> 5, d4 = idx & 31;
  int i0 = sidx[2*n], i1 = sidx[2*n+1];
  float g0 = gwn[2*n], g1 = gwn[2*n+1];
  float4 a = ((const float4*)x1)[idx];
  float4 u = ((const float4*)eo)[(size_t)i0 * 32 + d4];
  float4 w = ((const float4*)eo)[(size_t)i1 * 32 + d4];
  float4 o = {a.x + g0*u.x + g1*w.x, a.y + g0*u.y + g1*w.y,
              a.z + g0*u.z + g1*w.z, a.w + g0*u.w + g1*w.w};
  ((float4*)out)[idx] = o;
  if (idx == 0) {
    float aux = 0.f;
    for (int e = 0; e < E; ++e)
      aux += ((float)ecnt[e] * (1.f / 16384.f)) * (psum[e] * (1.f / 8192.f));
    out[N * D] = 8.f * aux;
  }
}

extern "C" void kernel_launch(void* const* d_in, const int* in_sizes, int n_in,
                              void* d_out, int out_size, void* d_ws, size_t ws_size,
                              hipStream_t stream) {
  const float* x    = (const float*)d_in[0];
  const float* ln1g = (const float*)d_in[1];
  const float* ln1b = (const float*)d_in[2];
  const float* wq   = (const float*)d_in[3];
  const float* wk   = (const float*)d_in[4];
  const float* wv   = (const float*)d_in[5];
  const float* wp   = (const float*)d_in[6];
  const float* bp   = (const float*)d_in[7];
  const float* ln2g = (const float*)d_in[8];
  const float* ln2b = (const float*)d_in[9];
  const float* wg   = (const float*)d_in[10];
  const float* w1   = (const float*)d_in[11];
  const float* b1   = (const float*)d_in[12];
  const float* w2   = (const float*)d_in[13];
  const float* b2   = (const float*)d_in[14];
  float* out = (float*)d_out;
  float* ws = (float*)d_ws;
  const size_t M = 1u << 20;  // 1M floats
  // layout (floats):
  // [0,1M)    A   : xn -> attn-out
  // [1M,2M)   Bq  : x1
  // [2M,2.5M) qh  (f16, 1M halves)   [2.5M,3M) kh   [3M,3.5M) vT
  // [3.5M,12.5M) part (18*8*NQ = 9M); eo reuses [3.5M,11.5M)
  // [12M,13M) xn2 (overlaps dead tail of part, after comb)
  // [13M,..)  ltok/sidx/gwn/psum/ecnt
  float* A  = ws;
  float* Bq = ws + 1 * M;
  _Float16* qh  = (_Float16*)(ws + 2 * M);
  _Float16* kh  = (_Float16*)(ws + 2 * M + M / 2);
  _Float16* vTh = (_Float16*)(ws + 3 * M);
  float* part = ws + 3 * M + M / 2;
  float* eo   = part;
  float* xn2  = ws + 12 * M;
  size_t G0 = 13 * M;
  int*   ltok = (int*)(ws + G0);             // 65536 ints
  int*   sidx = (int*)(ws + G0 + 65536);     // 16384 ints
  float* gwn  = ws + G0 + 81920;             // 16384 floats
  float* psum = ws + G0 + 98304;             // 8
  int*   ecnt = (int*)(ws + G0 + 98312);     // 8

  hipMemsetAsync(psum, 0, 64, stream);       // psum + ecnt
  ln_kernel<<<N, 64, 0, stream>>>(x, ln1g, ln1b, A);
  qkv_kernel<<<N / 16, 384, 0, stream>>>(A, wq, wk, wv, qh, kh, vTh);
  attn_mfma<<<dim3(32 * SPLITS, Bsz * H), 64, 0, stream>>>(qh, kh, vTh, part);
  attn_comb<<<NQ / 64, 64, 0, stream>>>(part, A);
  proj_kernel<<<N / 16, 128, 0, stream>>>(A, wp, bp, x, Bq);
  ln_kernel<<<N, 64, 0, stream>>>(Bq, ln2g, ln2b, xn2);
  gate_kernel<<<N / 64, 64, 0, stream>>>(xn2, wg, psum, ecnt, ltok, sidx, gwn);
  moe_kernel<<<dim3(128, E), 256, 0, stream>>>(xn2, w1, b1, w2, b2, ecnt, ltok, eo);
  finalize_kernel<<<(N * D / 4) / 256, 256, 0, stream>>>(Bq, eo, sidx, gwn, psum, ecnt, out);
}